// Round 1
// 696.613 us; speedup vs baseline: 1.3589x; 1.3589x over previous
//
#include <hip/hip_runtime.h>
#include <hip/hip_bf16.h>

// FutureLSTM: M=8192 rows; F=1024; H=512; 4H=2048; D=8 sequential steps.
// Round 4 (algebraic fusion): out_t@Wih^T folds into h_t@(Wih*Wcls+Whh)^T for t>=1,
// so the recurrent chain is 8 gates GEMMs (one K=1024, seven K=512) and the 8 cls
// GEMMs batch into one [65536,512]@[512,1024] GEMM at the end.
#define M_TOT 8192
#define FDIM  1024
#define HDIM  512
#define DSTEPS 8
#define BK 32

typedef __attribute__((ext_vector_type(8))) short short8;
typedef __attribute__((ext_vector_type(4))) float f32x4;

#define GLOAD_LDS16(gsrc, ldst)                                                        \
    __builtin_amdgcn_global_load_lds(                                                  \
        (__attribute__((address_space(1))) void*)(void*)(gsrc),                        \
        (__attribute__((address_space(3))) void*)(ldst), 16, 0, 0)

__device__ __forceinline__ unsigned short f2bf(float f) {
    unsigned u = __float_as_uint(f);
    return (unsigned short)((u + 0x7FFFu + ((u >> 16) & 1u)) >> 16);
}
__device__ __forceinline__ float sigm(float x) {
    return __builtin_amdgcn_rcpf(1.0f + __expf(-x));
}
__device__ __forceinline__ float tanh_(float x) {
    // tanh = 1 - 2/(1+e^{2x}); saturates to +/-1, no NaN for finite x.
    return 1.0f - 2.0f * __builtin_amdgcn_rcpf(1.0f + __expf(2.0f * x));
}

// ---------------------------------------------------------------------------
// gates = A @ W^T + bias, fused LSTM pointwise -> cbuf (fp32), hout (bf16).
// Single GEMM phase: t=0 uses W=Wih (ldk=1024, A=x, c=0); t>=1 uses W=Wcomb
// (ldk=512, A=h_{t-1}). W rows are gate-major: row g*512 + j.
// Tile: 128 rows x 64 hidden cols x all 4 gates; wave w owns cols w*16..+15 so
// each lane holds i/f/g/o for its (row,col) -> pointwise fused, no cross-lane.
// Grid 64x8 = 512 blocks = 2 blocks/CU.
// ---------------------------------------------------------------------------
__global__ __launch_bounds__(256, 2) void gates_kernel(
    const __hip_bfloat16* __restrict__ Ab,    // [8192, ldk] bf16
    const __hip_bfloat16* __restrict__ Wb,    // [2048, ldk] bf16, rows g*512+j
    const float* __restrict__ bias,           // [2048] fp32
    float* __restrict__ cbuf,                 // [8192,512] fp32 persistent
    __hip_bfloat16* __restrict__ hout,        // [8192,512] bf16
    int ldk, int first)
{
    __shared__ __align__(16) __hip_bfloat16 sA[128 * BK];      // 8 KB
    __shared__ __align__(16) __hip_bfloat16 sB[4 * 64 * BK];   // 16 KB (4 gate tiles)

    const int t    = threadIdx.x;
    const int wave = t >> 6;
    const int lane = t & 63;
    const int m0   = blockIdx.x * 128;
    const int j0   = blockIdx.y * 64;

    f32x4 acc[4][8];  // [gate][mi] -> 128 VGPRs
    #pragma unroll
    for (int g = 0; g < 4; ++g)
        #pragma unroll
        for (int mi = 0; mi < 8; ++mi) acc[g][mi] = (f32x4)(0.0f);

    const int row_ld = t >> 2;  // 0..63
    const int kh     = t & 3;
    const int fr     = lane & 15;
    const int quad   = lane >> 4;

    const int nchunk = ldk / BK;
    for (int kc = 0; kc < nchunk; ++kc) {
        __syncthreads();
        #pragma unroll
        for (int g = 0; g < 4; ++g) {
            GLOAD_LDS16(Wb + (size_t)(g * HDIM + j0 + row_ld) * ldk + kc * BK + kh * 8,
                        &sB[(g * 256 + t) * 8]);
        }
        GLOAD_LDS16(Ab + (size_t)(m0 + row_ld) * ldk + kc * BK + kh * 8, &sA[t * 8]);
        GLOAD_LDS16(Ab + (size_t)(m0 + 64 + row_ld) * ldk + kc * BK + kh * 8,
                    &sA[2048 + t * 8]);
        __syncthreads();

        short8 bfrag[4];
        #pragma unroll
        for (int g = 0; g < 4; ++g)
            bfrag[g] = *(const short8*)&sB[g * 64 * BK + (wave * 16 + fr) * BK + quad * 8];
        #pragma unroll
        for (int mi = 0; mi < 8; ++mi) {
            short8 afrag = *(const short8*)&sA[(mi * 16 + fr) * BK + quad * 8];
            #pragma unroll
            for (int g = 0; g < 4; ++g)
                acc[g][mi] = __builtin_amdgcn_mfma_f32_16x16x32_bf16(afrag, bfrag[g], acc[g][mi], 0, 0, 0);
        }
    }

    // Fused LSTM pointwise. C/D layout: col=lane&15, row=(lane>>4)*4+reg [m89/m91].
    const int col = j0 + wave * 16 + fr;
    const float bi = bias[col];
    const float bf = bias[HDIM + col];
    const float bg = bias[2 * HDIM + col];
    const float bo = bias[3 * HDIM + col];
    #pragma unroll
    for (int mi = 0; mi < 8; ++mi) {
        #pragma unroll
        for (int r = 0; r < 4; ++r) {
            const int row = m0 + mi * 16 + quad * 4 + r;
            const float iv = acc[0][mi][r] + bi;
            const float fv = acc[1][mi][r] + bf;
            const float gv = acc[2][mi][r] + bg;
            const float ov = acc[3][mi][r] + bo;
            const float cp = first ? 0.0f : cbuf[(size_t)row * HDIM + col];
            const float cn = sigm(fv) * cp + sigm(iv) * tanh_(gv);
            const float hn = sigm(ov) * tanh_(cn);
            cbuf[(size_t)row * HDIM + col] = cn;
            hout[(size_t)row * HDIM + col] = __hip_bfloat16(hn);
        }
    }
}

// ---------------------------------------------------------------------------
// Batched classifier: out[m, t, :] = hs[t*8192+m, :] @ Wcls^T + b_cls for all
// 8 steps at once. Tile 128 rows x 256 cols (4 sub-tiles of 64), 4 waves, same
// staging/fragment structure as gates_kernel (32 MFMA/wave/iter).
// Grid 512 x 4 = 2048 blocks. Each x-block sits inside one t-slice (8192%128==0).
// ---------------------------------------------------------------------------
__global__ __launch_bounds__(256, 2) void cls_kernel(
    const __hip_bfloat16* __restrict__ hs,     // [8*8192, 512] bf16 flat
    const __hip_bfloat16* __restrict__ Wclsb,  // [1024, 512] bf16
    const float* __restrict__ bcls,            // [1024] fp32
    float* __restrict__ dout)                  // [8192, 8, 1024] fp32
{
    __shared__ __align__(16) __hip_bfloat16 sA[128 * BK];      // 8 KB
    __shared__ __align__(16) __hip_bfloat16 sB[4 * 64 * BK];   // 16 KB

    const int t    = threadIdx.x;
    const int wave = t >> 6;
    const int lane = t & 63;
    const int m0   = blockIdx.x * 128;        // 0..65408
    const int n0   = blockIdx.y * 256;
    const int tt   = blockIdx.x >> 6;         // decode step for this block

    f32x4 acc[4][8];  // [n-subtile][mi]
    #pragma unroll
    for (int g = 0; g < 4; ++g)
        #pragma unroll
        for (int mi = 0; mi < 8; ++mi) acc[g][mi] = (f32x4)(0.0f);

    const int row_ld = t >> 2;
    const int kh     = t & 3;
    const int fr     = lane & 15;
    const int quad   = lane >> 4;

    for (int kc = 0; kc < HDIM / BK; ++kc) {
        __syncthreads();
        #pragma unroll
        for (int g = 0; g < 4; ++g) {
            GLOAD_LDS16(Wclsb + (size_t)(n0 + g * 64 + row_ld) * HDIM + kc * BK + kh * 8,
                        &sB[(g * 256 + t) * 8]);
        }
        GLOAD_LDS16(hs + (size_t)(m0 + row_ld) * HDIM + kc * BK + kh * 8, &sA[t * 8]);
        GLOAD_LDS16(hs + (size_t)(m0 + 64 + row_ld) * HDIM + kc * BK + kh * 8,
                    &sA[2048 + t * 8]);
        __syncthreads();

        short8 bfrag[4];
        #pragma unroll
        for (int g = 0; g < 4; ++g)
            bfrag[g] = *(const short8*)&sB[g * 64 * BK + (wave * 16 + fr) * BK + quad * 8];
        #pragma unroll
        for (int mi = 0; mi < 8; ++mi) {
            short8 afrag = *(const short8*)&sA[(mi * 16 + fr) * BK + quad * 8];
            #pragma unroll
            for (int g = 0; g < 4; ++g)
                acc[g][mi] = __builtin_amdgcn_mfma_f32_16x16x32_bf16(afrag, bfrag[g], acc[g][mi], 0, 0, 0);
        }
    }

    #pragma unroll
    for (int g = 0; g < 4; ++g) {
        const int col = n0 + g * 64 + wave * 16 + fr;
        const float bc = bcls[col];
        #pragma unroll
        for (int mi = 0; mi < 8; ++mi) {
            #pragma unroll
            for (int r = 0; r < 4; ++r) {
                const int row = m0 + mi * 16 + quad * 4 + r;
                const int m   = row & (M_TOT - 1);
                dout[(size_t)m * (DSTEPS * FDIM) + (size_t)tt * FDIM + col] =
                    acc[g][mi][r] + bc;
            }
        }
    }
}

// ---------------------------------------------------------------------------
// Wcomb = Wih(bf16) @ WclsT(bf16)^T (fp32 acc) + Whh(fp32) -> bf16 [2048,512].
// Classic 128x128 tile, 4 waves 2x2, K=1024. Grid 16x4. Runs once per launch.
// ---------------------------------------------------------------------------
__global__ __launch_bounds__(256) void fuse_gemm(
    const __hip_bfloat16* __restrict__ Wihb,   // [2048,1024] bf16
    const __hip_bfloat16* __restrict__ WclsT,  // [512,1024] bf16 (Wcls transposed)
    const float* __restrict__ Whh,             // [2048,512] fp32
    __hip_bfloat16* __restrict__ Wcombb)       // [2048,512] bf16
{
    __shared__ __align__(16) __hip_bfloat16 sA[128 * BK];
    __shared__ __align__(16) __hip_bfloat16 sB[128 * BK];

    const int t    = threadIdx.x;
    const int wave = t >> 6;
    const int lane = t & 63;
    const int wr   = wave >> 1;
    const int wc   = wave & 1;
    const int m0   = blockIdx.x * 128;
    const int n0   = blockIdx.y * 128;

    f32x4 acc[4][4];
    #pragma unroll
    for (int ni = 0; ni < 4; ++ni)
        #pragma unroll
        for (int mi = 0; mi < 4; ++mi) acc[ni][mi] = (f32x4)(0.0f);

    const int row_ld = t >> 2;
    const int kh     = t & 3;
    const int fr     = lane & 15;
    const int quad   = lane >> 4;

    for (int kc = 0; kc < FDIM / BK; ++kc) {
        __syncthreads();
        GLOAD_LDS16(Wihb + (size_t)(m0 + row_ld) * FDIM + kc * BK + kh * 8, &sA[t * 8]);
        GLOAD_LDS16(Wihb + (size_t)(m0 + 64 + row_ld) * FDIM + kc * BK + kh * 8,
                    &sA[2048 + t * 8]);
        GLOAD_LDS16(WclsT + (size_t)(n0 + row_ld) * FDIM + kc * BK + kh * 8, &sB[t * 8]);
        GLOAD_LDS16(WclsT + (size_t)(n0 + 64 + row_ld) * FDIM + kc * BK + kh * 8,
                    &sB[2048 + t * 8]);
        __syncthreads();

        short8 afrag[4], bfrag[4];
        #pragma unroll
        for (int i = 0; i < 4; ++i) {
            afrag[i] = *(const short8*)&sA[(wr * 64 + i * 16 + fr) * BK + quad * 8];
            bfrag[i] = *(const short8*)&sB[(wc * 64 + i * 16 + fr) * BK + quad * 8];
        }
        #pragma unroll
        for (int ni = 0; ni < 4; ++ni)
            #pragma unroll
            for (int mi = 0; mi < 4; ++mi)
                acc[ni][mi] = __builtin_amdgcn_mfma_f32_16x16x32_bf16(afrag[mi], bfrag[ni], acc[ni][mi], 0, 0, 0);
    }

    #pragma unroll
    for (int ni = 0; ni < 4; ++ni) {
        const int col = n0 + wc * 64 + ni * 16 + fr;
        #pragma unroll
        for (int mi = 0; mi < 4; ++mi) {
            #pragma unroll
            for (int r = 0; r < 4; ++r) {
                const int row = m0 + wr * 64 + mi * 16 + quad * 4 + r;
                const float v = acc[ni][mi][r] + Whh[(size_t)row * HDIM + col];
                Wcombb[(size_t)row * HDIM + col] = __hip_bfloat16(v);
            }
        }
    }
}

// WclsT[h,f] = bf16(Wcls[f,h]) via LDS-tiled transpose. Block (32,8), grid (32,16).
__global__ void transpose_cls(const float* __restrict__ Wcls,
                              __hip_bfloat16* __restrict__ WclsT) {
    __shared__ float tile[32][33];
    const int f0 = blockIdx.x * 32;
    const int h0 = blockIdx.y * 32;
    const int tx = threadIdx.x, ty = threadIdx.y;
    #pragma unroll
    for (int k = 0; k < 4; ++k)
        tile[ty + 8 * k][tx] = Wcls[(size_t)(f0 + ty + 8 * k) * HDIM + h0 + tx];
    __syncthreads();
    #pragma unroll
    for (int k = 0; k < 4; ++k)
        WclsT[(size_t)(h0 + ty + 8 * k) * FDIM + f0 + tx] =
            __hip_bfloat16(tile[tx][ty + 8 * k]);
}

// bias0[r] = bih+bhh; biasF[r] = bih+bhh + dot(Wih[r,:], bcls). One block per row.
__global__ void fuse_bias(const float* __restrict__ bih, const float* __restrict__ bhh,
                          const float* __restrict__ Wih, const float* __restrict__ bcls,
                          float* __restrict__ bias0, float* __restrict__ biasF) {
    const int r   = blockIdx.x;
    const int tid = threadIdx.x;
    float s = 0.0f;
    for (int k = tid; k < FDIM; k += 256) s += Wih[(size_t)r * FDIM + k] * bcls[k];
    #pragma unroll
    for (int off = 32; off; off >>= 1) s += __shfl_down(s, off, 64);
    __shared__ float red[4];
    if ((tid & 63) == 0) red[tid >> 6] = s;
    __syncthreads();
    if (tid == 0) {
        const float b = bih[r] + bhh[r];
        bias0[r] = b;
        biasF[r] = b + red[0] + red[1] + red[2] + red[3];
    }
}

__global__ void cvt_bf16(const float* __restrict__ src, __hip_bfloat16* __restrict__ dst, int n8) {
    int i = blockIdx.x * blockDim.x + threadIdx.x;
    if (i < n8) {
        const float4 a = ((const float4*)src)[2 * i];
        const float4 b = ((const float4*)src)[2 * i + 1];
        short8 v;
        v[0] = (short)f2bf(a.x); v[1] = (short)f2bf(a.y);
        v[2] = (short)f2bf(a.z); v[3] = (short)f2bf(a.w);
        v[4] = (short)f2bf(b.x); v[5] = (short)f2bf(b.y);
        v[6] = (short)f2bf(b.z); v[7] = (short)f2bf(b.w);
        ((short8*)dst)[i] = v;
    }
}

extern "C" void kernel_launch(void* const* d_in, const int* in_sizes, int n_in,
                              void* d_out, int out_size, void* d_ws, size_t ws_size,
                              hipStream_t stream) {
    const float* x    = (const float*)d_in[0];   // [8192,1024]
    const float* Wih  = (const float*)d_in[1];   // [2048,1024]
    const float* Whh  = (const float*)d_in[2];   // [2048,512]
    const float* bih  = (const float*)d_in[3];   // [2048]
    const float* bhh  = (const float*)d_in[4];   // [2048]
    const float* Wcls = (const float*)d_in[5];   // [1024,512]
    const float* bcls = (const float*)d_in[6];   // [1024]
    float* out = (float*)d_out;                  // [8192,8,1024] fp32

    // Workspace layout (~105 MB):
    char* ws = (char*)d_ws;
    __hip_bfloat16* Wihb   = (__hip_bfloat16*)(ws);                    //  4 MB
    __hip_bfloat16* Wclsb  = (__hip_bfloat16*)(ws + (4ull  << 20));    //  1 MB
    __hip_bfloat16* WclsT  = (__hip_bfloat16*)(ws + (5ull  << 20));    //  1 MB
    __hip_bfloat16* Wcombb = (__hip_bfloat16*)(ws + (6ull  << 20));    //  2 MB
    float*          bias0  = (float*)         (ws + (8ull  << 20));    //  8 KB
    float*          biasF  = (float*)         (ws + (8ull  << 20) + 32768);
    __hip_bfloat16* xb     = (__hip_bfloat16*)(ws + (9ull  << 20));    // 16 MB
    float*          cbuf   = (float*)         (ws + (25ull << 20));    // 16 MB
    __hip_bfloat16* hs     = (__hip_bfloat16*)(ws + (41ull << 20));    // 64 MB (8 x [8192,512])

    cvt_bf16<<<dim3(2048 * 1024 / 8 / 256), dim3(256), 0, stream>>>(Wih,  Wihb,  2048 * 1024 / 8);
    cvt_bf16<<<dim3(1024 * 512  / 8 / 256), dim3(256), 0, stream>>>(Wcls, Wclsb, 1024 * 512  / 8);
    cvt_bf16<<<dim3(8192 * 1024 / 8 / 256), dim3(256), 0, stream>>>(x,    xb,    8192 * 1024 / 8);
    transpose_cls<<<dim3(FDIM / 32, HDIM / 32), dim3(32, 8), 0, stream>>>(Wcls, WclsT);
    fuse_gemm<<<dim3(2048 / 128, HDIM / 128), dim3(256), 0, stream>>>(Wihb, WclsT, Whh, Wcombb);
    fuse_bias<<<dim3(2048), dim3(256), 0, stream>>>(bih, bhh, Wih, bcls, bias0, biasF);

    const size_t hstride = (size_t)M_TOT * HDIM;
    // t=0: gates from x with Wih (K=1024), c starts at 0.
    gates_kernel<<<dim3(M_TOT / 128, HDIM / 64), dim3(256), 0, stream>>>(
        xb, Wihb, bias0, cbuf, hs, FDIM, 1);
    // t=1..7: gates directly from h with fused Wcomb (K=512).
    for (int t = 1; t < DSTEPS; ++t) {
        gates_kernel<<<dim3(M_TOT / 128, HDIM / 64), dim3(256), 0, stream>>>(
            hs + (size_t)(t - 1) * hstride, Wcombb, biasF, cbuf, hs + (size_t)t * hstride,
            HDIM, 0);
    }
    // One batched classifier GEMM over all 8 h-states.
    cls_kernel<<<dim3(DSTEPS * M_TOT / 128, FDIM / 256), dim3(256), 0, stream>>>(
        hs, Wclsb, bcls, out);
}